// Round 1
// 497.539 us; speedup vs baseline: 1.2802x; 1.2802x over previous
//
#include <hip/hip_runtime.h>
#include <hip/hip_bf16.h>

// Problem constants (reference: WORLD_SIZE=8, M_LOCAL=1024, K=4096, N=4096)
#define M_TOTAL 8192
#define KDIM    4096
#define NDIM    4096

// GEMM tiling: 256x256 tile, BK=32, 512 threads (8 waves as 2M x 4N),
// per-wave output 128x64, 4-deep LDS ring with counted vmcnt pipeline.
#define BM 256
#define BN 256
#define BK 32
#define NT (KDIM / BK)          // 128 K-tiles
#define AREG (BM * BK)          // 8192 elems = 16 KiB per buffer (A)
#define BREG (BN * BK)          // 8192 elems = 16 KiB per buffer (B)
#define BUFE (AREG + BREG)      // 16384 elems = 32 KiB per ring slot
// ring = 4 slots = 128 KiB dynamic LDS

typedef __bf16 bf16x8 __attribute__((ext_vector_type(8)));
typedef float  f32x4  __attribute__((ext_vector_type(4)));

// ---------------------------------------------------------------------------
// fp32 -> bf16 (RNE), 8 elems/thread, 16B stores; A and W in one launch
// (unchanged from previous round — isolates the GEMM change)
// ---------------------------------------------------------------------------
__device__ __forceinline__ unsigned short f32_to_bf16_rne(unsigned u) {
    unsigned r = u + 0x7fffu + ((u >> 16) & 1u);
    return (unsigned short)(r >> 16);
}

__device__ __forceinline__ void cvt8(const float* __restrict__ s,
                                     unsigned short* __restrict__ d) {
    const uint4* sp = (const uint4*)s;
    uint4 x = sp[0];
    uint4 y = sp[1];
    uint4 o;
    o.x = (unsigned)f32_to_bf16_rne(x.x) | ((unsigned)f32_to_bf16_rne(x.y) << 16);
    o.y = (unsigned)f32_to_bf16_rne(x.z) | ((unsigned)f32_to_bf16_rne(x.w) << 16);
    o.z = (unsigned)f32_to_bf16_rne(y.x) | ((unsigned)f32_to_bf16_rne(y.y) << 16);
    o.w = (unsigned)f32_to_bf16_rne(y.z) | ((unsigned)f32_to_bf16_rne(y.w) << 16);
    *(uint4*)d = o;
}

__global__ __launch_bounds__(256) void cvt_both(const float* __restrict__ A,
                                                unsigned short* __restrict__ Abf,
                                                long nA,
                                                const float* __restrict__ W,
                                                unsigned short* __restrict__ Wbf) {
    long i = ((long)blockIdx.x * 256 + threadIdx.x) * 8;
    if (i < nA) {
        cvt8(A + i, Abf + i);
    } else {
        long j = i - nA;
        cvt8(W + j, Wbf + j);
    }
}

// ---------------------------------------------------------------------------
// async global -> LDS, 16B per lane (wave-uniform LDS base + lane*16)
// ---------------------------------------------------------------------------
__device__ __forceinline__ void gload_lds16(const unsigned short* g, unsigned short* l) {
    __builtin_amdgcn_global_load_lds(
        (const __attribute__((address_space(1))) unsigned int*)g,
        (__attribute__((address_space(3))) unsigned int*)l,
        16, 0, 0);
}

// ---------------------------------------------------------------------------
// C[M,N] = A[M,K] * B[N,K]^T   (bf16 in, fp32 out)
//
// Pipeline (the change this round): 4-slot LDS ring, stage tile t+3 while
// computing tile t. Raw s_barrier (no vmcnt drain) + counted s_waitcnt:
//
//   iter t:  s_waitcnt vmcnt(8)    // own loads: tiles t+1,t+2 may remain in
//                                  // flight; tile t's 4 loads are complete
//            s_barrier             // -> collectively, tile t fully in LDS
//            stage tile t+3 into ring[(t+3)&3]   (4 x global_load_lds / wave)
//            ds_read 12 frags from ring[t&3]; 32 MFMA (setprio 1 around)
//            s_waitcnt lgkmcnt(0)  // all my reads of ring[t&3] COMPLETE
//            s_barrier             // -> safe: iter t+1 stages tile t+4 into
//                                  //    ring[t&3], one barrier later
//
// Ledger: stage of tile X (iter X-3, after leading barrier) lands before the
// leading vmcnt+barrier of iter X (3 iterations ~ 1000cy of slack vs ~900cy
// HBM latency). Overwrite of ring[b] happens exactly one trailing
// lgkmcnt(0)+barrier after its last reader. vmcnt never drains to 0 until
// the 2-iteration epilogue (waits 8,8,4,0 over the last four tiles).
//
// LDS chunk swizzle: identical scheme to the previous (0-conflict-measured)
// kernel, generalized to 256 rows: slot s of row holds global 16B-chunk
// s ^ ((row>>1)&3); staging pre-swizzles the per-lane GLOBAL address so the
// LDS destination stays linear (global_load_lds requirement).
// ---------------------------------------------------------------------------
__global__ __launch_bounds__(512, 2) void gemm_bt(const unsigned short* __restrict__ A,
                                                  const unsigned short* __restrict__ B,
                                                  float* __restrict__ C) {
    extern __shared__ unsigned short smem[];

    const int tid  = threadIdx.x;
    const int wave = tid >> 6;
    const int lane = tid & 63;

    const int n0 = blockIdx.x * BN;
    const int m0 = blockIdx.y * BM;

    // ---- staging addresses: thread tid covers LDS bytes tid*16 of each 8KiB
    //      G::load; row = (tid>>2)+gi*128, stored slot = tid&3, so the global
    //      source chunk is (tid&3)^((tid>>3)&3)  [involution with read side]
    const int rsub = tid >> 2;                          // 0..127
    const int cswz = (tid & 3) ^ ((tid >> 3) & 3);      // swizzled src chunk
    const unsigned short* pA0 = A + (size_t)(m0 + rsub)       * KDIM + cswz * 8;
    const unsigned short* pA1 = A + (size_t)(m0 + 128 + rsub) * KDIM + cswz * 8;
    const unsigned short* pB0 = B + (size_t)(n0 + rsub)       * KDIM + cswz * 8;
    const unsigned short* pB1 = B + (size_t)(n0 + 128 + rsub) * KDIM + cswz * 8;
    const int woff = wave * 512;   // wave slice (1 KiB) within a G::load

    // ---- read addressing (wave (wm,wn) owns a 128x64 output block) ----
    const int wm   = wave >> 2;    // 0..1
    const int wn   = wave & 3;     // 0..3
    const int quad = lane >> 4;    // 0..3  (K-chunk index of A/B operands)
    const int r    = lane & 15;    // m (A) / n (B) / col (C)
    const int sidx = (quad ^ ((r >> 1) & 3)) * 8;   // swizzled read offset

    int aoff[8], boff[4];
#pragma unroll
    for (int mi = 0; mi < 8; ++mi) aoff[mi] = (wm * 128 + mi * 16 + r) * BK + sidx;
#pragma unroll
    for (int ni = 0; ni < 4; ++ni) boff[ni] = (wn * 64 + ni * 16 + r) * BK + sidx;

    f32x4 acc[8][4] = {};

#define SAp(b) (smem + (b) * BUFE)
#define SBq(b) (smem + (b) * BUFE + AREG)
#define STAGE(TS, SB) do {                                                  \
        const size_t so_ = (size_t)(TS) * BK;                               \
        gload_lds16(pA0 + so_, SAp(SB) + woff);                             \
        gload_lds16(pA1 + so_, SAp(SB) + 4096 + woff);                      \
        gload_lds16(pB0 + so_, SBq(SB) + woff);                             \
        gload_lds16(pB1 + so_, SBq(SB) + 4096 + woff);                      \
    } while (0)

    // prologue: tiles 0,1,2 -> ring slots 0,1,2  (12 loads/wave in flight)
    STAGE(0, 0);
    STAGE(1, 1);
    STAGE(2, 2);

#define GITER(RB, SB, VM, DOSTAGE, TS) do {                                 \
        asm volatile("s_waitcnt vmcnt(" #VM ")" ::: "memory");              \
        __builtin_amdgcn_s_barrier();                                       \
        asm volatile("" ::: "memory");                                      \
        if (DOSTAGE) STAGE(TS, SB);                                         \
        bf16x8 aF[8], bF[4];                                                \
        _Pragma("unroll")                                                   \
        for (int mi = 0; mi < 8; ++mi)                                      \
            aF[mi] = *(const bf16x8*)(SAp(RB) + aoff[mi]);                  \
        _Pragma("unroll")                                                   \
        for (int ni = 0; ni < 4; ++ni)                                      \
            bF[ni] = *(const bf16x8*)(SBq(RB) + boff[ni]);                  \
        __builtin_amdgcn_s_setprio(1);                                      \
        _Pragma("unroll")                                                   \
        for (int mi = 0; mi < 8; ++mi)                                      \
            _Pragma("unroll")                                               \
            for (int ni = 0; ni < 4; ++ni)                                  \
                acc[mi][ni] = __builtin_amdgcn_mfma_f32_16x16x32_bf16(      \
                    aF[mi], bF[ni], acc[mi][ni], 0, 0, 0);                  \
        __builtin_amdgcn_s_setprio(0);                                      \
        asm volatile("s_waitcnt lgkmcnt(0)" ::: "memory");                  \
        __builtin_amdgcn_s_barrier();                                       \
        asm volatile("" ::: "memory");                                      \
    } while (0)

    // main loop: t = 0..123 (31 groups of 4; ring slot = t&3, stage t+3)
    for (int g = 0; g < NT / 4 - 1; ++g) {
        const int t = g * 4;
        GITER(0, 3, 8, true, t + 3);
        GITER(1, 0, 8, true, t + 4);
        GITER(2, 1, 8, true, t + 5);
        GITER(3, 2, 8, true, t + 6);
    }
    // epilogue tiles 124..127: stage last tile, then drain 8 -> 8 -> 4 -> 0
    GITER(0, 3, 8, true, 127);
    GITER(1, 0, 8, false, 0);
    GITER(2, 1, 4, false, 0);
    GITER(3, 2, 0, false, 0);

#undef GITER
#undef STAGE
#undef SAp
#undef SBq

    // C/D layout: col = lane&15, row = quad*4 + reg  [verified m89/m91]
#pragma unroll
    for (int mi = 0; mi < 8; ++mi) {
        const int row = m0 + wm * 128 + mi * 16 + quad * 4;
#pragma unroll
        for (int ni = 0; ni < 4; ++ni) {
            const int col = n0 + wn * 64 + ni * 16 + r;
            float* p = C + (size_t)row * NDIM + col;
#pragma unroll
            for (int rr = 0; rr < 4; ++rr)
                p[(size_t)rr * NDIM] = acc[mi][ni][rr];
        }
    }
}

// ---------------------------------------------------------------------------
extern "C" void kernel_launch(void* const* d_in, const int* in_sizes, int n_in,
                              void* d_out, int out_size, void* d_ws, size_t ws_size,
                              hipStream_t stream) {
    const float* A = (const float*)d_in[0];   // [8,1024,4096] == [8192,4096]
    const float* W = (const float*)d_in[1];   // [4096,4096]  (N,K)
    float* out = (float*)d_out;               // [8192,4096] fp32

    unsigned short* Abf = (unsigned short*)d_ws;                       // 64 MiB
    unsigned short* Wbf = Abf + (size_t)M_TOTAL * KDIM;                // 32 MiB

    const long nA = (long)M_TOTAL * KDIM;     // 33,554,432
    const long nW = (long)NDIM * KDIM;        // 16,777,216
    const long nTot = nA + nW;

    cvt_both<<<(int)(nTot / 8 / 256), 256, 0, stream>>>(A, Abf, nA, W, Wbf);

    // 128 KiB dynamic LDS needs the attribute raised once (host-side call,
    // graph-capture safe: not a stream op)
    static bool attr_done = false;
    if (!attr_done) {
        hipFuncSetAttribute((const void*)gemm_bt,
                            hipFuncAttributeMaxDynamicSharedMemorySize, 128 * 1024);
        attr_done = true;
    }

    dim3 grid(NDIM / BN, M_TOTAL / BM);       // (16, 32) = 512 blocks
    gemm_bt<<<grid, 512, 128 * 1024, stream>>>(Abf, Wbf, out);
}

// Round 2
// 488.463 us; speedup vs baseline: 1.3040x; 1.0186x over previous
//
#include <hip/hip_runtime.h>
#include <hip/hip_bf16.h>

// Problem constants (reference: WORLD_SIZE=8, M_LOCAL=1024, K=4096, N=4096)
#define M_TOTAL 8192
#define KDIM    4096
#define NDIM    4096

// GEMM tiling: 256x256 tile, BK=32, 512 threads (8 waves as 2M x 4N),
// per-wave output 128x64, 4-deep LDS ring with counted vmcnt pipeline.
#define BM 256
#define BN 256
#define BK 32
#define NT (KDIM / BK)          // 128 K-tiles
#define AREG (BM * BK)          // 8192 elems = 16 KiB per buffer (A)
#define BREG (BN * BK)          // 8192 elems = 16 KiB per buffer (B)
#define BUFE (AREG + BREG)      // 16384 elems = 32 KiB per ring slot
// ring = 4 slots = 128 KiB dynamic LDS

typedef __bf16 bf16x8 __attribute__((ext_vector_type(8)));
typedef float  f32x4  __attribute__((ext_vector_type(4)));

// ---------------------------------------------------------------------------
// fp32 -> bf16 (RNE), 8 elems/thread, 16B stores; A and W in one launch
// (unchanged — isolates the GEMM sync-structure change)
// ---------------------------------------------------------------------------
__device__ __forceinline__ unsigned short f32_to_bf16_rne(unsigned u) {
    unsigned r = u + 0x7fffu + ((u >> 16) & 1u);
    return (unsigned short)(r >> 16);
}

__device__ __forceinline__ void cvt8(const float* __restrict__ s,
                                     unsigned short* __restrict__ d) {
    const uint4* sp = (const uint4*)s;
    uint4 x = sp[0];
    uint4 y = sp[1];
    uint4 o;
    o.x = (unsigned)f32_to_bf16_rne(x.x) | ((unsigned)f32_to_bf16_rne(x.y) << 16);
    o.y = (unsigned)f32_to_bf16_rne(x.z) | ((unsigned)f32_to_bf16_rne(x.w) << 16);
    o.z = (unsigned)f32_to_bf16_rne(y.x) | ((unsigned)f32_to_bf16_rne(y.y) << 16);
    o.w = (unsigned)f32_to_bf16_rne(y.z) | ((unsigned)f32_to_bf16_rne(y.w) << 16);
    *(uint4*)d = o;
}

__global__ __launch_bounds__(256) void cvt_both(const float* __restrict__ A,
                                                unsigned short* __restrict__ Abf,
                                                long nA,
                                                const float* __restrict__ W,
                                                unsigned short* __restrict__ Wbf) {
    long i = ((long)blockIdx.x * 256 + threadIdx.x) * 8;
    if (i < nA) {
        cvt8(A + i, Abf + i);
    } else {
        long j = i - nA;
        cvt8(W + j, Wbf + j);
    }
}

// ---------------------------------------------------------------------------
// async global -> LDS, 16B per lane (wave-uniform LDS base + lane*16)
// ---------------------------------------------------------------------------
__device__ __forceinline__ void gload_lds16(const unsigned short* g, unsigned short* l) {
    __builtin_amdgcn_global_load_lds(
        (const __attribute__((address_space(1))) unsigned int*)g,
        (__attribute__((address_space(3))) unsigned int*)l,
        16, 0, 0);
}

// ---------------------------------------------------------------------------
// C[M,N] = A[M,K] * B[N,K]^T   (bf16 in, fp32 out)
//
// CHANGE THIS ROUND: single barrier per K-tile (was 2). Ledger:
//
//   iter t:  s_waitcnt vmcnt(8)    // own tile-t loads retired (t+1,t+2 may
//                                  //   stay in flight; FIFO retire, m135)
//            s_barrier             // collectively: (a) tile t fully in LDS;
//                                  //   (b) every wave executed its trailing
//                                  //   lgkmcnt(0) of iter t-1 -> ALL reads of
//                                  //   tile t-1 COMPLETE -> slot (t-1)&3 free
//            stage tile t+3 -> ring[(t+3)&3] == ring[(t-1)&3]   (safe by (b))
//            ds_read 12 frags from ring[t&3]; 32 MFMA (setprio-wrapped,
//              compiler emits fine-grained lgkmcnt interleave)
//            s_waitcnt lgkmcnt(0)  // drain MY reads of ring[t&3]; nearly
//                                  //   free post-MFMA; makes (b) hold at the
//                                  //   NEXT barrier. No second s_barrier.
//
// Fence audit: ds_reads can't sink past the trailing lgkmcnt ("memory"
// clobber) nor hoist above the post-barrier fence; STAGE can't hoist above
// the vmcnt asm. MFMA reordering (reg-only) is race-irrelevant: the hazard
// is ds_read execution vs LDS overwrite, guarded by the counted lgkm drain.
// vmcnt never reaches 0 until the final 2 iterations (8,...,8,8,4,0).
//
// LDS chunk swizzle (unchanged, 0 conflicts measured): slot s of row r holds
// global 16B-chunk s ^ ((r>>1)&3); staging pre-swizzles the per-lane GLOBAL
// address so the LDS destination stays linear (global_load_lds requirement).
// ---------------------------------------------------------------------------
__global__ __launch_bounds__(512, 2) void gemm_bt(const unsigned short* __restrict__ A,
                                                  const unsigned short* __restrict__ B,
                                                  float* __restrict__ C) {
    extern __shared__ unsigned short smem[];

    const int tid  = threadIdx.x;
    const int wave = tid >> 6;
    const int lane = tid & 63;

    const int n0 = blockIdx.x * BN;
    const int m0 = blockIdx.y * BM;

    // ---- staging addresses: thread tid covers LDS bytes tid*16 of each 8KiB
    //      G::load; row = (tid>>2)+gi*128, stored slot = tid&3, so the global
    //      source chunk is (tid&3)^((tid>>3)&3)  [involution with read side]
    const int rsub = tid >> 2;                          // 0..127
    const int cswz = (tid & 3) ^ ((tid >> 3) & 3);      // swizzled src chunk
    const unsigned short* pA0 = A + (size_t)(m0 + rsub)       * KDIM + cswz * 8;
    const unsigned short* pA1 = A + (size_t)(m0 + 128 + rsub) * KDIM + cswz * 8;
    const unsigned short* pB0 = B + (size_t)(n0 + rsub)       * KDIM + cswz * 8;
    const unsigned short* pB1 = B + (size_t)(n0 + 128 + rsub) * KDIM + cswz * 8;
    const int woff = wave * 512;   // wave slice (1 KiB) within a G::load

    // ---- read addressing (wave (wm,wn) owns a 128x64 output block) ----
    const int wm   = wave >> 2;    // 0..1
    const int wn   = wave & 3;     // 0..3
    const int quad = lane >> 4;    // 0..3  (K-chunk index of A/B operands)
    const int r    = lane & 15;    // m (A) / n (B) / col (C)
    const int sidx = (quad ^ ((r >> 1) & 3)) * 8;   // swizzled read offset

    int aoff[8], boff[4];
#pragma unroll
    for (int mi = 0; mi < 8; ++mi) aoff[mi] = (wm * 128 + mi * 16 + r) * BK + sidx;
#pragma unroll
    for (int ni = 0; ni < 4; ++ni) boff[ni] = (wn * 64 + ni * 16 + r) * BK + sidx;

    f32x4 acc[8][4] = {};

#define SAp(b) (smem + (b) * BUFE)
#define SBq(b) (smem + (b) * BUFE + AREG)
#define STAGE(TS, SB) do {                                                  \
        const size_t so_ = (size_t)(TS) * BK;                               \
        gload_lds16(pA0 + so_, SAp(SB) + woff);                             \
        gload_lds16(pA1 + so_, SAp(SB) + 4096 + woff);                      \
        gload_lds16(pB0 + so_, SBq(SB) + woff);                             \
        gload_lds16(pB1 + so_, SBq(SB) + 4096 + woff);                      \
    } while (0)

    // prologue: tiles 0,1,2 -> ring slots 0,1,2  (12 loads/wave in flight)
    STAGE(0, 0);
    STAGE(1, 1);
    STAGE(2, 2);

#define GITER(RB, SB, VM, DOSTAGE, TS) do {                                 \
        asm volatile("s_waitcnt vmcnt(" #VM ")" ::: "memory");              \
        __builtin_amdgcn_s_barrier();                                       \
        asm volatile("" ::: "memory");                                      \
        if (DOSTAGE) STAGE(TS, SB);                                         \
        bf16x8 aF[8], bF[4];                                                \
        _Pragma("unroll")                                                   \
        for (int mi = 0; mi < 8; ++mi)                                      \
            aF[mi] = *(const bf16x8*)(SAp(RB) + aoff[mi]);                  \
        _Pragma("unroll")                                                   \
        for (int ni = 0; ni < 4; ++ni)                                      \
            bF[ni] = *(const bf16x8*)(SBq(RB) + boff[ni]);                  \
        __builtin_amdgcn_s_setprio(1);                                      \
        _Pragma("unroll")                                                   \
        for (int mi = 0; mi < 8; ++mi)                                      \
            _Pragma("unroll")                                               \
            for (int ni = 0; ni < 4; ++ni)                                  \
                acc[mi][ni] = __builtin_amdgcn_mfma_f32_16x16x32_bf16(      \
                    aF[mi], bF[ni], acc[mi][ni], 0, 0, 0);                  \
        __builtin_amdgcn_s_setprio(0);                                      \
        asm volatile("s_waitcnt lgkmcnt(0)" ::: "memory");                  \
    } while (0)

    // main loop: t = 0..123 (31 groups of 4; ring slot = t&3, stage t+3)
    for (int g = 0; g < NT / 4 - 1; ++g) {
        const int t = g * 4;
        GITER(0, 3, 8, true, t + 3);
        GITER(1, 0, 8, true, t + 4);
        GITER(2, 1, 8, true, t + 5);
        GITER(3, 2, 8, true, t + 6);
    }
    // tiles 124..127: stage last tile, then drain 8 -> 8 -> 4 -> 0
    GITER(0, 3, 8, true, 127);
    GITER(1, 0, 8, false, 0);
    GITER(2, 1, 4, false, 0);
    GITER(3, 2, 0, false, 0);

#undef GITER
#undef STAGE
#undef SAp
#undef SBq

    // C/D layout: col = lane&15, row = quad*4 + reg  [verified m89/m91]
#pragma unroll
    for (int mi = 0; mi < 8; ++mi) {
        const int row = m0 + wm * 128 + mi * 16 + quad * 4;
#pragma unroll
        for (int ni = 0; ni < 4; ++ni) {
            const int col = n0 + wn * 64 + ni * 16 + r;
            float* p = C + (size_t)row * NDIM + col;
#pragma unroll
            for (int rr = 0; rr < 4; ++rr)
                p[(size_t)rr * NDIM] = acc[mi][ni][rr];
        }
    }
}

// ---------------------------------------------------------------------------
extern "C" void kernel_launch(void* const* d_in, const int* in_sizes, int n_in,
                              void* d_out, int out_size, void* d_ws, size_t ws_size,
                              hipStream_t stream) {
    const float* A = (const float*)d_in[0];   // [8,1024,4096] == [8192,4096]
    const float* W = (const float*)d_in[1];   // [4096,4096]  (N,K)
    float* out = (float*)d_out;               // [8192,4096] fp32

    unsigned short* Abf = (unsigned short*)d_ws;                       // 64 MiB
    unsigned short* Wbf = Abf + (size_t)M_TOTAL * KDIM;                // 32 MiB

    const long nA = (long)M_TOTAL * KDIM;     // 33,554,432
    const long nW = (long)NDIM * KDIM;        // 16,777,216
    const long nTot = nA + nW;

    cvt_both<<<(int)(nTot / 8 / 256), 256, 0, stream>>>(A, Abf, nA, W, Wbf);

    // 128 KiB dynamic LDS needs the attribute raised once (host-side call,
    // graph-capture safe: not a stream op)
    static bool attr_done = false;
    if (!attr_done) {
        hipFuncSetAttribute((const void*)gemm_bt,
                            hipFuncAttributeMaxDynamicSharedMemorySize, 128 * 1024);
        attr_done = true;
    }

    dim3 grid(NDIM / BN, M_TOTAL / BM);       // (16, 32) = 512 blocks
    gemm_bt<<<grid, 512, 128 * 1024, stream>>>(Abf, Wbf, out);
}